// Round 9
// baseline (280.134 us; speedup 1.0000x reference)
//
#include <hip/hip_runtime.h>
#include <math.h>

// ContextualLoss via MFMA bf16.
// X,T = reshape(50,16384)[10:50]; S = Xn^T Tn (K=40 padded to 64, bf16 MFMA);
// per input-column i: m=min_j S, M=max_j S, Z=sum_j exp((1-S/(m+eps))/h);
// CXmax_i = max(w(m),w(M))/Z (w monotone in S); loss = -log(max_i CXmax_i).
//
// R9: (a) native v_exp_f32 via __builtin_amdgcn_exp2f (exp2f without
// -ffast-math is a ~5-instr OCML sequence -- 3x the issue slots); (b) 32
// rows/wave (a[2][2]) to cut live regs ~64->~48 so total incl. MFMA acc
// fits the 8-waves/SIMD boundary (512-reg/SIMD file: 8 waves need <=64).
// R8 showed occupancy pinned at 40% regardless of grid size -> register-
// footprint-capped at 4 waves/SIMD, not grid-capped. JS back to 16.

#define NCOL   16384
#define KDIM   40
#define KPAD   64
#define ROW0   10
#define EPSILON 1e-5f
#define COS_EPS 1e-8f
#define Q5L2E   7.2134752044448169f   // 5 * log2(e)  (1/h = 5)
#define JS      16                    // j slices
#define JSL     (NCOL / JS)           // 1024 j per slice
#define JT_PER  (JSL / 16)            // 64 16-wide j tiles per wave
#define MI_T    2                     // 16-row M-subtiles per wave (32 rows)
#define RPB     (MI_T * 16 * 4)       // rows per block (4 waves) = 128
#define IBLK    (NCOL / RPB)          // 128 i-blocks

#if __has_builtin(__builtin_amdgcn_exp2f)
#define EXP2F(x) __builtin_amdgcn_exp2f(x)
#else
#define EXP2F(x) __expf((x) * 0.69314718055994531f)
#endif

typedef __attribute__((ext_vector_type(8))) short bf16x8;
typedef __attribute__((ext_vector_type(4))) float f32x4;

static __device__ __forceinline__ unsigned short f2bf(float f) {
    unsigned u = __float_as_uint(f);           // RNE float->bf16
    u += 0x7FFFu + ((u >> 16) & 1u);
    return (unsigned short)(u >> 16);
}

// ---------------- kernel 1: mu + column normalize + bf16 pack ----------------
__global__ __launch_bounds__(256) void ctx_norm_kernel(
        const float* __restrict__ inp, const float* __restrict__ tgt,
        short* __restrict__ xb, short* __restrict__ tb) {
    int n = blockIdx.x * 256 + threadIdx.x;
    float t[KDIM], x[KDIM];
    float mu = 0.f;
#pragma unroll
    for (int r = 0; r < KDIM; ++r) { t[r] = tgt[(ROW0 + r) * NCOL + n]; mu += t[r]; }
    mu *= (1.0f / KDIM);
    float nt = 0.f;
#pragma unroll
    for (int r = 0; r < KDIM; ++r) { t[r] -= mu; nt = fmaf(t[r], t[r], nt); }
    float rnt = 1.0f / fmaxf(sqrtf(nt), COS_EPS);
    float nx = 0.f;
#pragma unroll
    for (int r = 0; r < KDIM; ++r) {
        x[r] = inp[(ROW0 + r) * NCOL + n] - mu;
        nx = fmaf(x[r], x[r], nx);
    }
    float rnx = 1.0f / fmaxf(sqrtf(nx), COS_EPS);

    short* to = tb + (size_t)n * KPAD;
    short* xo = xb + (size_t)n * KPAD;
#pragma unroll
    for (int q = 0; q < KDIM / 4; ++q) {        // q = 0..9: data
        ushort4 wt, wx;
        wt.x = f2bf(t[4*q+0] * rnt); wt.y = f2bf(t[4*q+1] * rnt);
        wt.z = f2bf(t[4*q+2] * rnt); wt.w = f2bf(t[4*q+3] * rnt);
        wx.x = f2bf(x[4*q+0] * rnx); wx.y = f2bf(x[4*q+1] * rnx);
        wx.z = f2bf(x[4*q+2] * rnx); wx.w = f2bf(x[4*q+3] * rnx);
        *reinterpret_cast<ushort4*>(to + 4*q) = wt;
        *reinterpret_cast<ushort4*>(xo + 4*q) = wx;
    }
    ushort4 z = {0, 0, 0, 0};
#pragma unroll
    for (int q = KDIM / 4; q < KPAD / 4; ++q) { // q = 10..15: zero pad
        *reinterpret_cast<ushort4*>(to + 4*q) = z;
        *reinterpret_cast<ushort4*>(xo + 4*q) = z;
    }
}

// ---------------- kernel 2: MFMA row min/max over a j slice ----------------
// grid (IBLK, JS), 256 thr = 4 waves. Wave owns 32 i-rows (2 M-subtiles),
// scans JSL j's. A-frags register-resident; B-frags straight from global
// (wave-span 1KB, L1/L2-hit). C/D layout: col=lane&15, row=(lane>>4)*4+reg.
__global__ __launch_bounds__(256) void ctx_stats_kernel(
        const short* __restrict__ xb, const short* __restrict__ tb,
        float* __restrict__ pmin, float* __restrict__ pmax) {
    const int tid = threadIdx.x;
    const int wave = tid >> 6, l = tid & 63;
    const int la = l & 15, g = l >> 4;
    const int ibase = blockIdx.x * RPB + wave * (MI_T * 16);
    const int js = blockIdx.y;

    bf16x8 a[MI_T][2];
#pragma unroll
    for (int mi = 0; mi < MI_T; ++mi)
#pragma unroll
        for (int ks = 0; ks < 2; ++ks)
            a[mi][ks] = *reinterpret_cast<const bf16x8*>(
                xb + (size_t)(ibase + mi * 16 + la) * KPAD + ks * 32 + g * 8);

    float vmn[MI_T][4], vmx[MI_T][4];
#pragma unroll
    for (int mi = 0; mi < MI_T; ++mi)
#pragma unroll
        for (int r = 0; r < 4; ++r) { vmn[mi][r] = 3.4e38f; vmx[mi][r] = -3.4e38f; }

    const f32x4 zero4 = {0.f, 0.f, 0.f, 0.f};
    const short* bp = tb + (size_t)(js * JSL + la) * KPAD + g * 8;
#pragma unroll 2
    for (int jt = 0; jt < JT_PER; ++jt) {
        bf16x8 b0 = *reinterpret_cast<const bf16x8*>(bp);
        bf16x8 b1 = *reinterpret_cast<const bf16x8*>(bp + 32);
        bp += 16 * KPAD;
#pragma unroll
        for (int mi = 0; mi < MI_T; ++mi) {
            f32x4 acc = __builtin_amdgcn_mfma_f32_16x16x32_bf16(a[mi][0], b0, zero4, 0, 0, 0);
            acc = __builtin_amdgcn_mfma_f32_16x16x32_bf16(a[mi][1], b1, acc, 0, 0, 0);
#pragma unroll
            for (int r = 0; r < 4; ++r) {
                vmn[mi][r] = fminf(vmn[mi][r], acc[r]);
                vmx[mi][r] = fmaxf(vmx[mi][r], acc[r]);
            }
        }
    }
    // reduce over the 16 column-lanes of each 16-lane group
#pragma unroll
    for (int off = 1; off < 16; off <<= 1)
#pragma unroll
        for (int mi = 0; mi < MI_T; ++mi)
#pragma unroll
            for (int r = 0; r < 4; ++r) {
                vmn[mi][r] = fminf(vmn[mi][r], __shfl_xor(vmn[mi][r], off, 64));
                vmx[mi][r] = fmaxf(vmx[mi][r], __shfl_xor(vmx[mi][r], off, 64));
            }
    if (la == 0) {
#pragma unroll
        for (int mi = 0; mi < MI_T; ++mi)
#pragma unroll
            for (int r = 0; r < 4; ++r) {
                int row = ibase + mi * 16 + g * 4 + r;
                pmin[js * NCOL + row] = vmn[mi][r];
                pmax[js * NCOL + row] = vmx[mi][r];
            }
    }
}

// ---------------- kernel 3: fold JS partials -> final row min/max ----------------
__global__ __launch_bounds__(256) void ctx_fold_kernel(
        const float* __restrict__ pmin, const float* __restrict__ pmax,
        float* __restrict__ rmin, float* __restrict__ rmax) {
    int i = blockIdx.x * 256 + threadIdx.x;
    float m = pmin[i], M = pmax[i];
#pragma unroll
    for (int s = 1; s < JS; ++s) {
        m = fminf(m, pmin[s * NCOL + i]);
        M = fmaxf(M, pmax[s * NCOL + i]);
    }
    rmin[i] = m; rmax[i] = M;
}

// ---------------- kernel 4: MFMA row sum of exp over a j slice ----------------
// w = exp((1-S*c)/h) = exp2(fma(S, -Q5L2E*c, Q5L2E)), c = 1/(m+eps) per row.
__global__ __launch_bounds__(256) void ctx_sumexp_kernel(
        const short* __restrict__ xb, const short* __restrict__ tb,
        const float* __restrict__ rmin, float* __restrict__ psum) {
    const int tid = threadIdx.x;
    const int wave = tid >> 6, l = tid & 63;
    const int la = l & 15, g = l >> 4;
    const int ibase = blockIdx.x * RPB + wave * (MI_T * 16);
    const int js = blockIdx.y;

    bf16x8 a[MI_T][2];
#pragma unroll
    for (int mi = 0; mi < MI_T; ++mi)
#pragma unroll
        for (int ks = 0; ks < 2; ++ks)
            a[mi][ks] = *reinterpret_cast<const bf16x8*>(
                xb + (size_t)(ibase + mi * 16 + la) * KPAD + ks * 32 + g * 8);

    float p[MI_T][4], zs[MI_T][4];
#pragma unroll
    for (int mi = 0; mi < MI_T; ++mi)
#pragma unroll
        for (int r = 0; r < 4; ++r) {
            int row = ibase + mi * 16 + g * 4 + r;
            float c = 1.0f / (rmin[row] + EPSILON);
            p[mi][r] = -Q5L2E * c;
            zs[mi][r] = 0.f;
        }

    const f32x4 zero4 = {0.f, 0.f, 0.f, 0.f};
    const short* bp = tb + (size_t)(js * JSL + la) * KPAD + g * 8;
#pragma unroll 2
    for (int jt = 0; jt < JT_PER; ++jt) {
        bf16x8 b0 = *reinterpret_cast<const bf16x8*>(bp);
        bf16x8 b1 = *reinterpret_cast<const bf16x8*>(bp + 32);
        bp += 16 * KPAD;
#pragma unroll
        for (int mi = 0; mi < MI_T; ++mi) {
            f32x4 acc = __builtin_amdgcn_mfma_f32_16x16x32_bf16(a[mi][0], b0, zero4, 0, 0, 0);
            acc = __builtin_amdgcn_mfma_f32_16x16x32_bf16(a[mi][1], b1, acc, 0, 0, 0);
#pragma unroll
            for (int r = 0; r < 4; ++r)
                zs[mi][r] += EXP2F(fmaf(acc[r], p[mi][r], Q5L2E));
        }
    }
#pragma unroll
    for (int off = 1; off < 16; off <<= 1)
#pragma unroll
        for (int mi = 0; mi < MI_T; ++mi)
#pragma unroll
            for (int r = 0; r < 4; ++r)
                zs[mi][r] += __shfl_xor(zs[mi][r], off, 64);
    if (la == 0) {
#pragma unroll
        for (int mi = 0; mi < MI_T; ++mi)
#pragma unroll
            for (int r = 0; r < 4; ++r) {
                int row = ibase + mi * 16 + g * 4 + r;
                psum[js * NCOL + row] = zs[mi][r];
            }
    }
}

// ---------------- kernel 5: per-row CX-max, per-block max ----------------
__global__ __launch_bounds__(256) void ctx_reduce_kernel(
        const float* __restrict__ rmin, const float* __restrict__ rmax,
        const float* __restrict__ psum, float* __restrict__ blkmax) {
    int tid = threadIdx.x;
    int i = blockIdx.x * 256 + tid;
    float m = rmin[i], M = rmax[i], Z = psum[i];
#pragma unroll
    for (int s = 1; s < JS; ++s) Z += psum[s * NCOL + i];
    float c = 1.0f / (m + EPSILON);
    float w1 = EXP2F(fmaf(M, -Q5L2E * c, Q5L2E));
    float w2 = EXP2F(fmaf(m, -Q5L2E * c, Q5L2E));
    float best = fmaxf(w1, w2) / Z;   // CX strictly positive

    for (int off = 32; off > 0; off >>= 1)
        best = fmaxf(best, __shfl_down(best, off, 64));
    __shared__ float red[4];
    if ((tid & 63) == 0) red[tid >> 6] = best;
    __syncthreads();
    if (tid == 0)
        blkmax[blockIdx.x] = fmaxf(fmaxf(red[0], red[1]), fmaxf(red[2], red[3]));
}

// ---------------- kernel 6: 64 -> 1, -log ----------------
__global__ void ctx_loss_kernel(const float* __restrict__ blkmax,
                                float* __restrict__ out) {
    int tid = threadIdx.x;       // one wave of 64
    float best = blkmax[tid];
    for (int off = 32; off > 0; off >>= 1)
        best = fmaxf(best, __shfl_down(best, off, 64));
    if (tid == 0) out[0] = -logf(best);
}

extern "C" void kernel_launch(void* const* d_in, const int* in_sizes, int n_in,
                              void* d_out, int out_size, void* d_ws, size_t ws_size,
                              hipStream_t stream) {
    const float* inp = (const float*)d_in[0];
    const float* tgt = (const float*)d_in[1];
    float* out = (float*)d_out;

    // ws layout (bytes):
    //   xb     bf16 [16384][64]  2 MB
    //   tb     bf16 [16384][64]  2 MB
    //   pmin   f32  [16][16384]  1 MB
    //   pmax   f32  [16][16384]  1 MB
    //   psum   f32  [16][16384]  1 MB
    //   rmin   f32  [16384]      64 KB
    //   rmax   f32  [16384]      64 KB
    //   blkmax f32  [64]
    char* base = (char*)d_ws;
    short* xb     = (short*)(base);
    short* tb     = (short*)(base + (size_t)2 * NCOL * KPAD);           // +2MB
    float* pmin   = (float*)(base + (size_t)4 * NCOL * KPAD);           // +4MB
    float* pmax   = pmin + (size_t)JS * NCOL;
    float* psum   = pmax + (size_t)JS * NCOL;
    float* rmin   = psum + (size_t)JS * NCOL;
    float* rmax   = rmin + NCOL;
    float* blkmax = rmax + NCOL;

    dim3 grid2(IBLK, JS);
    ctx_norm_kernel  <<<NCOL / 256, 256, 0, stream>>>(inp, tgt, xb, tb);
    ctx_stats_kernel <<<grid2, 256, 0, stream>>>(xb, tb, pmin, pmax);
    ctx_fold_kernel  <<<NCOL / 256, 256, 0, stream>>>(pmin, pmax, rmin, rmax);
    ctx_sumexp_kernel<<<grid2, 256, 0, stream>>>(xb, tb, rmin, psum);
    ctx_reduce_kernel<<<NCOL / 256, 256, 0, stream>>>(rmin, rmax, psum, blkmax);
    ctx_loss_kernel  <<<1, 64, 0, stream>>>(blkmax, out);
}

// Round 10
// 143.364 us; speedup vs baseline: 1.9540x; 1.9540x over previous
//
#include <hip/hip_runtime.h>
#include <math.h>

// ContextualLoss via MFMA bf16.
// X,T = reshape(50,16384)[10:50]; S = Xn^T Tn (K=40 padded to 64, bf16 MFMA);
// per input-column i: m=min_j S, M=max_j S, Z=sum_j exp((1-S/(m+eps))/h);
// CXmax_i = max(w(m),w(M))/Z (w monotone in S); loss = -log(max_i CXmax_i).
//
// R10 = R6 structure (MI_T=4: 64 rows/wave, JS=16, lb(256,4)) + native
// v_exp_f32 via __builtin_amdgcn_exp2f ONLY. R9's MI_T=2 halved per-B-load
// compute amortization and tripled both hot kernels (VALUBusy 64->13%,
// VMEM-latency-bound) -- reverted. exp2f w/o -ffast-math is a multi-instr
// OCML sequence; native exp cuts the per-element epilogue ~6 -> 3 slots.

#define NCOL   16384
#define KDIM   40
#define KPAD   64
#define ROW0   10
#define EPSILON 1e-5f
#define COS_EPS 1e-8f
#define Q5L2E   7.2134752044448169f   // 5 * log2(e)  (1/h = 5)
#define JS      16                    // j slices
#define JSL     (NCOL / JS)           // 1024 j per slice
#define JT_PER  (JSL / 16)            // 64 16-wide j tiles per wave

#if __has_builtin(__builtin_amdgcn_exp2f)
#define EXP2F(x) __builtin_amdgcn_exp2f(x)
#else
#define EXP2F(x) __expf((x) * 0.69314718055994531f)
#endif

typedef __attribute__((ext_vector_type(8))) short bf16x8;
typedef __attribute__((ext_vector_type(4))) float f32x4;

static __device__ __forceinline__ unsigned short f2bf(float f) {
    unsigned u = __float_as_uint(f);           // RNE float->bf16
    u += 0x7FFFu + ((u >> 16) & 1u);
    return (unsigned short)(u >> 16);
}

// ---------------- kernel 1: mu + column normalize + bf16 pack ----------------
__global__ __launch_bounds__(256) void ctx_norm_kernel(
        const float* __restrict__ inp, const float* __restrict__ tgt,
        short* __restrict__ xb, short* __restrict__ tb) {
    int n = blockIdx.x * 256 + threadIdx.x;
    float t[KDIM], x[KDIM];
    float mu = 0.f;
#pragma unroll
    for (int r = 0; r < KDIM; ++r) { t[r] = tgt[(ROW0 + r) * NCOL + n]; mu += t[r]; }
    mu *= (1.0f / KDIM);
    float nt = 0.f;
#pragma unroll
    for (int r = 0; r < KDIM; ++r) { t[r] -= mu; nt = fmaf(t[r], t[r], nt); }
    float rnt = 1.0f / fmaxf(sqrtf(nt), COS_EPS);
    float nx = 0.f;
#pragma unroll
    for (int r = 0; r < KDIM; ++r) {
        x[r] = inp[(ROW0 + r) * NCOL + n] - mu;
        nx = fmaf(x[r], x[r], nx);
    }
    float rnx = 1.0f / fmaxf(sqrtf(nx), COS_EPS);

    short* to = tb + (size_t)n * KPAD;
    short* xo = xb + (size_t)n * KPAD;
#pragma unroll
    for (int q = 0; q < KDIM / 4; ++q) {        // q = 0..9: data
        ushort4 wt, wx;
        wt.x = f2bf(t[4*q+0] * rnt); wt.y = f2bf(t[4*q+1] * rnt);
        wt.z = f2bf(t[4*q+2] * rnt); wt.w = f2bf(t[4*q+3] * rnt);
        wx.x = f2bf(x[4*q+0] * rnx); wx.y = f2bf(x[4*q+1] * rnx);
        wx.z = f2bf(x[4*q+2] * rnx); wx.w = f2bf(x[4*q+3] * rnx);
        *reinterpret_cast<ushort4*>(to + 4*q) = wt;
        *reinterpret_cast<ushort4*>(xo + 4*q) = wx;
    }
    ushort4 z = {0, 0, 0, 0};
#pragma unroll
    for (int q = KDIM / 4; q < KPAD / 4; ++q) { // q = 10..15: zero pad
        *reinterpret_cast<ushort4*>(to + 4*q) = z;
        *reinterpret_cast<ushort4*>(xo + 4*q) = z;
    }
}

// ---------------- kernel 2: MFMA row min/max over a j slice ----------------
// grid (64, JS), 256 thr = 4 waves. Wave owns 64 i-rows (4 MFMA M-subtiles),
// scans JSL j's. A-frags register-resident; B-frags straight from global
// (wave-span 1KB, L1/L2-hit). C/D layout: col=lane&15, row=(lane>>4)*4+reg.
__global__ __launch_bounds__(256, 4) void ctx_stats_kernel(
        const short* __restrict__ xb, const short* __restrict__ tb,
        float* __restrict__ pmin, float* __restrict__ pmax) {
    const int tid = threadIdx.x;
    const int wave = tid >> 6, l = tid & 63;
    const int la = l & 15, g = l >> 4;
    const int ibase = blockIdx.x * 256 + wave * 64;
    const int js = blockIdx.y;

    bf16x8 a[4][2];
#pragma unroll
    for (int mi = 0; mi < 4; ++mi)
#pragma unroll
        for (int ks = 0; ks < 2; ++ks)
            a[mi][ks] = *reinterpret_cast<const bf16x8*>(
                xb + (size_t)(ibase + mi * 16 + la) * KPAD + ks * 32 + g * 8);

    float vmn[4][4], vmx[4][4];
#pragma unroll
    for (int mi = 0; mi < 4; ++mi)
#pragma unroll
        for (int r = 0; r < 4; ++r) { vmn[mi][r] = 3.4e38f; vmx[mi][r] = -3.4e38f; }

    const f32x4 zero4 = {0.f, 0.f, 0.f, 0.f};
    const short* bp = tb + (size_t)(js * JSL + la) * KPAD + g * 8;
#pragma unroll 2
    for (int jt = 0; jt < JT_PER; ++jt) {
        bf16x8 b0 = *reinterpret_cast<const bf16x8*>(bp);
        bf16x8 b1 = *reinterpret_cast<const bf16x8*>(bp + 32);
        bp += 16 * KPAD;
#pragma unroll
        for (int mi = 0; mi < 4; ++mi) {
            f32x4 acc = __builtin_amdgcn_mfma_f32_16x16x32_bf16(a[mi][0], b0, zero4, 0, 0, 0);
            acc = __builtin_amdgcn_mfma_f32_16x16x32_bf16(a[mi][1], b1, acc, 0, 0, 0);
#pragma unroll
            for (int r = 0; r < 4; ++r) {
                vmn[mi][r] = fminf(vmn[mi][r], acc[r]);
                vmx[mi][r] = fmaxf(vmx[mi][r], acc[r]);
            }
        }
    }
    // reduce over the 16 column-lanes of each 16-lane group
#pragma unroll
    for (int off = 1; off < 16; off <<= 1)
#pragma unroll
        for (int mi = 0; mi < 4; ++mi)
#pragma unroll
            for (int r = 0; r < 4; ++r) {
                vmn[mi][r] = fminf(vmn[mi][r], __shfl_xor(vmn[mi][r], off, 64));
                vmx[mi][r] = fmaxf(vmx[mi][r], __shfl_xor(vmx[mi][r], off, 64));
            }
    if (la == 0) {
#pragma unroll
        for (int mi = 0; mi < 4; ++mi)
#pragma unroll
            for (int r = 0; r < 4; ++r) {
                int row = ibase + mi * 16 + g * 4 + r;
                pmin[js * NCOL + row] = vmn[mi][r];
                pmax[js * NCOL + row] = vmx[mi][r];
            }
    }
}

// ---------------- kernel 3: fold JS partials -> final row min/max ----------------
__global__ __launch_bounds__(256) void ctx_fold_kernel(
        const float* __restrict__ pmin, const float* __restrict__ pmax,
        float* __restrict__ rmin, float* __restrict__ rmax) {
    int i = blockIdx.x * 256 + threadIdx.x;
    float m = pmin[i], M = pmax[i];
#pragma unroll
    for (int s = 1; s < JS; ++s) {
        m = fminf(m, pmin[s * NCOL + i]);
        M = fmaxf(M, pmax[s * NCOL + i]);
    }
    rmin[i] = m; rmax[i] = M;
}

// ---------------- kernel 4: MFMA row sum of exp over a j slice ----------------
// w = exp((1-S*c)/h) = exp2(fma(S, -Q5L2E*c, Q5L2E)), c = 1/(m+eps) per row.
__global__ __launch_bounds__(256, 4) void ctx_sumexp_kernel(
        const short* __restrict__ xb, const short* __restrict__ tb,
        const float* __restrict__ rmin, float* __restrict__ psum) {
    const int tid = threadIdx.x;
    const int wave = tid >> 6, l = tid & 63;
    const int la = l & 15, g = l >> 4;
    const int ibase = blockIdx.x * 256 + wave * 64;
    const int js = blockIdx.y;

    bf16x8 a[4][2];
#pragma unroll
    for (int mi = 0; mi < 4; ++mi)
#pragma unroll
        for (int ks = 0; ks < 2; ++ks)
            a[mi][ks] = *reinterpret_cast<const bf16x8*>(
                xb + (size_t)(ibase + mi * 16 + la) * KPAD + ks * 32 + g * 8);

    float p[4][4], zs[4][4];
#pragma unroll
    for (int mi = 0; mi < 4; ++mi)
#pragma unroll
        for (int r = 0; r < 4; ++r) {
            int row = ibase + mi * 16 + g * 4 + r;
            float c = 1.0f / (rmin[row] + EPSILON);
            p[mi][r] = -Q5L2E * c;
            zs[mi][r] = 0.f;
        }

    const f32x4 zero4 = {0.f, 0.f, 0.f, 0.f};
    const short* bp = tb + (size_t)(js * JSL + la) * KPAD + g * 8;
#pragma unroll 2
    for (int jt = 0; jt < JT_PER; ++jt) {
        bf16x8 b0 = *reinterpret_cast<const bf16x8*>(bp);
        bf16x8 b1 = *reinterpret_cast<const bf16x8*>(bp + 32);
        bp += 16 * KPAD;
#pragma unroll
        for (int mi = 0; mi < 4; ++mi) {
            f32x4 acc = __builtin_amdgcn_mfma_f32_16x16x32_bf16(a[mi][0], b0, zero4, 0, 0, 0);
            acc = __builtin_amdgcn_mfma_f32_16x16x32_bf16(a[mi][1], b1, acc, 0, 0, 0);
#pragma unroll
            for (int r = 0; r < 4; ++r)
                zs[mi][r] += EXP2F(fmaf(acc[r], p[mi][r], Q5L2E));
        }
    }
#pragma unroll
    for (int off = 1; off < 16; off <<= 1)
#pragma unroll
        for (int mi = 0; mi < 4; ++mi)
#pragma unroll
            for (int r = 0; r < 4; ++r)
                zs[mi][r] += __shfl_xor(zs[mi][r], off, 64);
    if (la == 0) {
#pragma unroll
        for (int mi = 0; mi < 4; ++mi)
#pragma unroll
            for (int r = 0; r < 4; ++r) {
                int row = ibase + mi * 16 + g * 4 + r;
                psum[js * NCOL + row] = zs[mi][r];
            }
    }
}

// ---------------- kernel 5: per-row CX-max, per-block max ----------------
__global__ __launch_bounds__(256) void ctx_reduce_kernel(
        const float* __restrict__ rmin, const float* __restrict__ rmax,
        const float* __restrict__ psum, float* __restrict__ blkmax) {
    int tid = threadIdx.x;
    int i = blockIdx.x * 256 + tid;
    float m = rmin[i], M = rmax[i], Z = psum[i];
#pragma unroll
    for (int s = 1; s < JS; ++s) Z += psum[s * NCOL + i];
    float c = 1.0f / (m + EPSILON);
    float w1 = EXP2F(fmaf(M, -Q5L2E * c, Q5L2E));
    float w2 = EXP2F(fmaf(m, -Q5L2E * c, Q5L2E));
    float best = fmaxf(w1, w2) / Z;   // CX strictly positive

    for (int off = 32; off > 0; off >>= 1)
        best = fmaxf(best, __shfl_down(best, off, 64));
    __shared__ float red[4];
    if ((tid & 63) == 0) red[tid >> 6] = best;
    __syncthreads();
    if (tid == 0)
        blkmax[blockIdx.x] = fmaxf(fmaxf(red[0], red[1]), fmaxf(red[2], red[3]));
}

// ---------------- kernel 6: 64 -> 1, -log ----------------
__global__ void ctx_loss_kernel(const float* __restrict__ blkmax,
                                float* __restrict__ out) {
    int tid = threadIdx.x;       // one wave of 64
    float best = blkmax[tid];
    for (int off = 32; off > 0; off >>= 1)
        best = fmaxf(best, __shfl_down(best, off, 64));
    if (tid == 0) out[0] = -logf(best);
}

extern "C" void kernel_launch(void* const* d_in, const int* in_sizes, int n_in,
                              void* d_out, int out_size, void* d_ws, size_t ws_size,
                              hipStream_t stream) {
    const float* inp = (const float*)d_in[0];
    const float* tgt = (const float*)d_in[1];
    float* out = (float*)d_out;

    // ws layout (bytes):
    //   xb     bf16 [16384][64]  2 MB
    //   tb     bf16 [16384][64]  2 MB
    //   pmin   f32  [16][16384]  1 MB
    //   pmax   f32  [16][16384]  1 MB
    //   psum   f32  [16][16384]  1 MB
    //   rmin   f32  [16384]      64 KB
    //   rmax   f32  [16384]      64 KB
    //   blkmax f32  [64]
    char* base = (char*)d_ws;
    short* xb     = (short*)(base);
    short* tb     = (short*)(base + (size_t)2 * NCOL * KPAD);           // +2MB
    float* pmin   = (float*)(base + (size_t)4 * NCOL * KPAD);           // +4MB
    float* pmax   = pmin + (size_t)JS * NCOL;
    float* psum   = pmax + (size_t)JS * NCOL;
    float* rmin   = psum + (size_t)JS * NCOL;
    float* rmax   = rmin + NCOL;
    float* blkmax = rmax + NCOL;

    dim3 grid2(NCOL / 256, JS);
    ctx_norm_kernel  <<<NCOL / 256, 256, 0, stream>>>(inp, tgt, xb, tb);
    ctx_stats_kernel <<<grid2, 256, 0, stream>>>(xb, tb, pmin, pmax);
    ctx_fold_kernel  <<<NCOL / 256, 256, 0, stream>>>(pmin, pmax, rmin, rmax);
    ctx_sumexp_kernel<<<grid2, 256, 0, stream>>>(xb, tb, rmin, psum);
    ctx_reduce_kernel<<<NCOL / 256, 256, 0, stream>>>(rmin, rmax, psum, blkmax);
    ctx_loss_kernel  <<<1, 64, 0, stream>>>(blkmax, out);
}

// Round 11
// 94.245 us; speedup vs baseline: 2.9724x; 1.5212x over previous
//
#include <hip/hip_runtime.h>
#include <math.h>

// ContextualLoss via MFMA bf16.
// X,T = reshape(50,16384)[10:50]; S = Xn^T Tn (K=40 padded to 64, bf16 MFMA);
// per input-column i: m=min_j S, M=max_j S, Z=sum_j exp((1-S/(m+eps))/h);
// CXmax_i = max(w(m),w(M))/Z (w monotone in S); loss = -log(max_i CXmax_i).
//
// R11 = R10 + LDS double-buffered B staging (T14 issue-early/write-late,
// one barrier per chunk) with XOR slot swizzle (slot ^= row&7) on both
// ds_write and ds_read (row stride 128B would otherwise be a 16-way bank
// conflict). R10 counters: VALUBusy 41%, MfmaUtil 19%, Occ 42% -> latency-
// stalled on the per-tile global B-load chain; occupancy axis is dead
// (R8 grid-2x: no change; R9 reg-shrink: regression), so hide latency
// in-wave via bulk prefetch.

#define NCOL   16384
#define KDIM   40
#define KPAD   64
#define ROW0   10
#define EPSILON 1e-5f
#define COS_EPS 1e-8f
#define Q5L2E   7.2134752044448169f   // 5 * log2(e)  (1/h = 5)
#define JS      16                    // j slices
#define JSL     (NCOL / JS)           // 1024 j per slice
#define CHJ     128                   // j per staged chunk (16 KB)
#define NCH     (JSL / CHJ)           // 8 chunks per slice
#define TPC     (CHJ / 16)            // 8 16-wide j tiles per chunk

#if __has_builtin(__builtin_amdgcn_exp2f)
#define EXP2F(x) __builtin_amdgcn_exp2f(x)
#else
#define EXP2F(x) __expf((x) * 0.69314718055994531f)
#endif

typedef __attribute__((ext_vector_type(8))) short bf16x8;
typedef __attribute__((ext_vector_type(4))) float f32x4;

static __device__ __forceinline__ unsigned short f2bf(float f) {
    unsigned u = __float_as_uint(f);           // RNE float->bf16
    u += 0x7FFFu + ((u >> 16) & 1u);
    return (unsigned short)(u >> 16);
}

// ---------------- kernel 1: mu + column normalize + bf16 pack ----------------
__global__ __launch_bounds__(256) void ctx_norm_kernel(
        const float* __restrict__ inp, const float* __restrict__ tgt,
        short* __restrict__ xb, short* __restrict__ tb) {
    int n = blockIdx.x * 256 + threadIdx.x;
    float t[KDIM], x[KDIM];
    float mu = 0.f;
#pragma unroll
    for (int r = 0; r < KDIM; ++r) { t[r] = tgt[(ROW0 + r) * NCOL + n]; mu += t[r]; }
    mu *= (1.0f / KDIM);
    float nt = 0.f;
#pragma unroll
    for (int r = 0; r < KDIM; ++r) { t[r] -= mu; nt = fmaf(t[r], t[r], nt); }
    float rnt = 1.0f / fmaxf(sqrtf(nt), COS_EPS);
    float nx = 0.f;
#pragma unroll
    for (int r = 0; r < KDIM; ++r) {
        x[r] = inp[(ROW0 + r) * NCOL + n] - mu;
        nx = fmaf(x[r], x[r], nx);
    }
    float rnx = 1.0f / fmaxf(sqrtf(nx), COS_EPS);

    short* to = tb + (size_t)n * KPAD;
    short* xo = xb + (size_t)n * KPAD;
#pragma unroll
    for (int q = 0; q < KDIM / 4; ++q) {        // q = 0..9: data
        ushort4 wt, wx;
        wt.x = f2bf(t[4*q+0] * rnt); wt.y = f2bf(t[4*q+1] * rnt);
        wt.z = f2bf(t[4*q+2] * rnt); wt.w = f2bf(t[4*q+3] * rnt);
        wx.x = f2bf(x[4*q+0] * rnx); wx.y = f2bf(x[4*q+1] * rnx);
        wx.z = f2bf(x[4*q+2] * rnx); wx.w = f2bf(x[4*q+3] * rnx);
        *reinterpret_cast<ushort4*>(to + 4*q) = wt;
        *reinterpret_cast<ushort4*>(xo + 4*q) = wx;
    }
    ushort4 z = {0, 0, 0, 0};
#pragma unroll
    for (int q = KDIM / 4; q < KPAD / 4; ++q) { // q = 10..15: zero pad
        *reinterpret_cast<ushort4*>(to + 4*q) = z;
        *reinterpret_cast<ushort4*>(xo + 4*q) = z;
    }
}

// Staging helpers: chunk = CHJ rows x 128 B. Thread t moves 4 x 16 B:
// logical byte offset o = t*16 + r*4096 -> row = t/8 + r*32, slot = t&7.
// LDS address swizzle: phys_slot = slot ^ (row & 7)  (involution, rule #21).
#define STAGE_LOAD(st, src, tid)                                              \
    _Pragma("unroll")                                                         \
    for (int r_ = 0; r_ < 4; ++r_)                                            \
        (st)[r_] = *reinterpret_cast<const bf16x8*>((src) + (tid) * 8 + r_ * 2048);

#define STAGE_WRITE(buf, st, tid)                                             \
    {                                                                         \
        const int row_ = (tid) >> 3, s0_ = (tid) & 7;                         \
        _Pragma("unroll")                                                     \
        for (int r_ = 0; r_ < 4; ++r_) {                                      \
            int rr_ = row_ + r_ * 32;                                         \
            *reinterpret_cast<bf16x8*>(                                       \
                &(buf)[rr_ * 64 + ((s0_ ^ (rr_ & 7)) * 8)]) = (st)[r_];       \
        }                                                                     \
    }

// ---------------- kernel 2: MFMA row min/max over a j slice ----------------
// grid (64, JS), 256 thr = 4 waves. Wave owns 64 i-rows (4 MFMA M-subtiles).
// B staged via LDS double buffer, shared by all 4 waves.
__global__ __launch_bounds__(256, 4) void ctx_stats_kernel(
        const short* __restrict__ xb, const short* __restrict__ tb,
        float* __restrict__ pmin, float* __restrict__ pmax) {
    const int tid = threadIdx.x;
    const int wave = tid >> 6, l = tid & 63;
    const int la = l & 15, g = l >> 4;
    const int ibase = blockIdx.x * 256 + wave * 64;
    const int js = blockIdx.y;

    __shared__ __align__(16) short ldsb[2][CHJ * KPAD];   // 2 x 16 KB

    bf16x8 a[4][2];
#pragma unroll
    for (int mi = 0; mi < 4; ++mi)
#pragma unroll
        for (int ks = 0; ks < 2; ++ks)
            a[mi][ks] = *reinterpret_cast<const bf16x8*>(
                xb + (size_t)(ibase + mi * 16 + la) * KPAD + ks * 32 + g * 8);

    float vmn[4][4], vmx[4][4];
#pragma unroll
    for (int mi = 0; mi < 4; ++mi)
#pragma unroll
        for (int r = 0; r < 4; ++r) { vmn[mi][r] = 3.4e38f; vmx[mi][r] = -3.4e38f; }

    const short* tbase = tb + (size_t)js * JSL * KPAD;

    {   // prologue: stage chunk 0 into buffer 0
        bf16x8 st[4];
        STAGE_LOAD(st, tbase, tid);
        STAGE_WRITE(ldsb[0], st, tid);
    }
    __syncthreads();

    const f32x4 zero4 = {0.f, 0.f, 0.f, 0.f};
    int cb = 0;
    for (int ch = 0; ch < NCH; ++ch) {
        bf16x8 st[4];
        const bool more = (ch + 1 < NCH);
        if (more) {                       // issue next-chunk loads EARLY
            const short* src = tbase + (size_t)(ch + 1) * CHJ * KPAD;
            STAGE_LOAD(st, src, tid);
        }
#pragma unroll 2
        for (int jj = 0; jj < TPC; ++jj) {
            const int lr = jj * 16 + la;
            const short* lp = &ldsb[cb][lr * 64];
            bf16x8 b0 = *reinterpret_cast<const bf16x8*>(lp + ((g    ) ^ (lr & 7)) * 8);
            bf16x8 b1 = *reinterpret_cast<const bf16x8*>(lp + ((g + 4) ^ (lr & 7)) * 8);
#pragma unroll
            for (int mi = 0; mi < 4; ++mi) {
                f32x4 acc = __builtin_amdgcn_mfma_f32_16x16x32_bf16(a[mi][0], b0, zero4, 0, 0, 0);
                acc = __builtin_amdgcn_mfma_f32_16x16x32_bf16(a[mi][1], b1, acc, 0, 0, 0);
#pragma unroll
                for (int r = 0; r < 4; ++r) {
                    vmn[mi][r] = fminf(vmn[mi][r], acc[r]);
                    vmx[mi][r] = fmaxf(vmx[mi][r], acc[r]);
                }
            }
        }
        if (more) STAGE_WRITE(ldsb[cb ^ 1], st, tid);   // write LATE
        __syncthreads();
        cb ^= 1;
    }

    // reduce over the 16 column-lanes of each 16-lane group
#pragma unroll
    for (int off = 1; off < 16; off <<= 1)
#pragma unroll
        for (int mi = 0; mi < 4; ++mi)
#pragma unroll
            for (int r = 0; r < 4; ++r) {
                vmn[mi][r] = fminf(vmn[mi][r], __shfl_xor(vmn[mi][r], off, 64));
                vmx[mi][r] = fmaxf(vmx[mi][r], __shfl_xor(vmx[mi][r], off, 64));
            }
    if (la == 0) {
#pragma unroll
        for (int mi = 0; mi < 4; ++mi)
#pragma unroll
            for (int r = 0; r < 4; ++r) {
                int row = ibase + mi * 16 + g * 4 + r;
                pmin[js * NCOL + row] = vmn[mi][r];
                pmax[js * NCOL + row] = vmx[mi][r];
            }
    }
}

// ---------------- kernel 3: fold JS partials -> final row min/max ----------------
__global__ __launch_bounds__(256) void ctx_fold_kernel(
        const float* __restrict__ pmin, const float* __restrict__ pmax,
        float* __restrict__ rmin, float* __restrict__ rmax) {
    int i = blockIdx.x * 256 + threadIdx.x;
    float m = pmin[i], M = pmax[i];
#pragma unroll
    for (int s = 1; s < JS; ++s) {
        m = fminf(m, pmin[s * NCOL + i]);
        M = fmaxf(M, pmax[s * NCOL + i]);
    }
    rmin[i] = m; rmax[i] = M;
}

// ---------------- kernel 4: MFMA row sum of exp over a j slice ----------------
// w = exp((1-S*c)/h) = exp2(fma(S, -Q5L2E*c, Q5L2E)), c = 1/(m+eps) per row.
__global__ __launch_bounds__(256, 4) void ctx_sumexp_kernel(
        const short* __restrict__ xb, const short* __restrict__ tb,
        const float* __restrict__ rmin, float* __restrict__ psum) {
    const int tid = threadIdx.x;
    const int wave = tid >> 6, l = tid & 63;
    const int la = l & 15, g = l >> 4;
    const int ibase = blockIdx.x * 256 + wave * 64;
    const int js = blockIdx.y;

    __shared__ __align__(16) short ldsb[2][CHJ * KPAD];   // 2 x 16 KB

    bf16x8 a[4][2];
#pragma unroll
    for (int mi = 0; mi < 4; ++mi)
#pragma unroll
        for (int ks = 0; ks < 2; ++ks)
            a[mi][ks] = *reinterpret_cast<const bf16x8*>(
                xb + (size_t)(ibase + mi * 16 + la) * KPAD + ks * 32 + g * 8);

    float p[4][4], zs[4][4];
#pragma unroll
    for (int mi = 0; mi < 4; ++mi)
#pragma unroll
        for (int r = 0; r < 4; ++r) {
            int row = ibase + mi * 16 + g * 4 + r;
            float c = 1.0f / (rmin[row] + EPSILON);
            p[mi][r] = -Q5L2E * c;
            zs[mi][r] = 0.f;
        }

    const short* tbase = tb + (size_t)js * JSL * KPAD;

    {   // prologue: stage chunk 0 into buffer 0
        bf16x8 st[4];
        STAGE_LOAD(st, tbase, tid);
        STAGE_WRITE(ldsb[0], st, tid);
    }
    __syncthreads();

    const f32x4 zero4 = {0.f, 0.f, 0.f, 0.f};
    int cb = 0;
    for (int ch = 0; ch < NCH; ++ch) {
        bf16x8 st[4];
        const bool more = (ch + 1 < NCH);
        if (more) {                       // issue next-chunk loads EARLY
            const short* src = tbase + (size_t)(ch + 1) * CHJ * KPAD;
            STAGE_LOAD(st, src, tid);
        }
#pragma unroll 2
        for (int jj = 0; jj < TPC; ++jj) {
            const int lr = jj * 16 + la;
            const short* lp = &ldsb[cb][lr * 64];
            bf16x8 b0 = *reinterpret_cast<const bf16x8*>(lp + ((g    ) ^ (lr & 7)) * 8);
            bf16x8 b1 = *reinterpret_cast<const bf16x8*>(lp + ((g + 4) ^ (lr & 7)) * 8);
#pragma unroll
            for (int mi = 0; mi < 4; ++mi) {
                f32x4 acc = __builtin_amdgcn_mfma_f32_16x16x32_bf16(a[mi][0], b0, zero4, 0, 0, 0);
                acc = __builtin_amdgcn_mfma_f32_16x16x32_bf16(a[mi][1], b1, acc, 0, 0, 0);
#pragma unroll
                for (int r = 0; r < 4; ++r)
                    zs[mi][r] += EXP2F(fmaf(acc[r], p[mi][r], Q5L2E));
            }
        }
        if (more) STAGE_WRITE(ldsb[cb ^ 1], st, tid);   // write LATE
        __syncthreads();
        cb ^= 1;
    }

#pragma unroll
    for (int off = 1; off < 16; off <<= 1)
#pragma unroll
        for (int mi = 0; mi < 4; ++mi)
#pragma unroll
            for (int r = 0; r < 4; ++r)
                zs[mi][r] += __shfl_xor(zs[mi][r], off, 64);
    if (la == 0) {
#pragma unroll
        for (int mi = 0; mi < 4; ++mi)
#pragma unroll
            for (int r = 0; r < 4; ++r) {
                int row = ibase + mi * 16 + g * 4 + r;
                psum[js * NCOL + row] = zs[mi][r];
            }
    }
}

// ---------------- kernel 5: per-row CX-max, per-block max ----------------
__global__ __launch_bounds__(256) void ctx_reduce_kernel(
        const float* __restrict__ rmin, const float* __restrict__ rmax,
        const float* __restrict__ psum, float* __restrict__ blkmax) {
    int tid = threadIdx.x;
    int i = blockIdx.x * 256 + tid;
    float m = rmin[i], M = rmax[i], Z = psum[i];
#pragma unroll
    for (int s = 1; s < JS; ++s) Z += psum[s * NCOL + i];
    float c = 1.0f / (m + EPSILON);
    float w1 = EXP2F(fmaf(M, -Q5L2E * c, Q5L2E));
    float w2 = EXP2F(fmaf(m, -Q5L2E * c, Q5L2E));
    float best = fmaxf(w1, w2) / Z;   // CX strictly positive

    for (int off = 32; off > 0; off >>= 1)
        best = fmaxf(best, __shfl_down(best, off, 64));
    __shared__ float red[4];
    if ((tid & 63) == 0) red[tid >> 6] = best;
    __syncthreads();
    if (tid == 0)
        blkmax[blockIdx.x] = fmaxf(fmaxf(red[0], red[1]), fmaxf(red[2], red[3]));
}

// ---------------- kernel 6: 64 -> 1, -log ----------------
__global__ void ctx_loss_kernel(const float* __restrict__ blkmax,
                                float* __restrict__ out) {
    int tid = threadIdx.x;       // one wave of 64
    float best = blkmax[tid];
    for (int off = 32; off > 0; off >>= 1)
        best = fmaxf(best, __shfl_down(best, off, 64));
    if (tid == 0) out[0] = -logf(best);
}

extern "C" void kernel_launch(void* const* d_in, const int* in_sizes, int n_in,
                              void* d_out, int out_size, void* d_ws, size_t ws_size,
                              hipStream_t stream) {
    const float* inp = (const float*)d_in[0];
    const float* tgt = (const float*)d_in[1];
    float* out = (float*)d_out;

    // ws layout (bytes):
    //   xb     bf16 [16384][64]  2 MB
    //   tb     bf16 [16384][64]  2 MB
    //   pmin   f32  [16][16384]  1 MB
    //   pmax   f32  [16][16384]  1 MB
    //   psum   f32  [16][16384]  1 MB
    //   rmin   f32  [16384]      64 KB
    //   rmax   f32  [16384]      64 KB
    //   blkmax f32  [64]
    char* base = (char*)d_ws;
    short* xb     = (short*)(base);
    short* tb     = (short*)(base + (size_t)2 * NCOL * KPAD);           // +2MB
    float* pmin   = (float*)(base + (size_t)4 * NCOL * KPAD);           // +4MB
    float* pmax   = pmin + (size_t)JS * NCOL;
    float* psum   = pmax + (size_t)JS * NCOL;
    float* rmin   = psum + (size_t)JS * NCOL;
    float* rmax   = rmin + NCOL;
    float* blkmax = rmax + NCOL;

    dim3 grid2(NCOL / 256, JS);
    ctx_norm_kernel  <<<NCOL / 256, 256, 0, stream>>>(inp, tgt, xb, tb);
    ctx_stats_kernel <<<grid2, 256, 0, stream>>>(xb, tb, pmin, pmax);
    ctx_fold_kernel  <<<NCOL / 256, 256, 0, stream>>>(pmin, pmax, rmin, rmax);
    ctx_sumexp_kernel<<<grid2, 256, 0, stream>>>(xb, tb, rmin, psum);
    ctx_reduce_kernel<<<NCOL / 256, 256, 0, stream>>>(rmin, rmax, psum, blkmax);
    ctx_loss_kernel  <<<1, 64, 0, stream>>>(blkmax, out);
}